// Round 4
// baseline (24496.605 us; speedup 1.0000x reference)
//
#include <hip/hip_runtime.h>
#include <stdint.h>

// ============================================================================
// RecurrentAutoEncoder (2-layer LSTM enc + 2-layer LSTM dec + FC).
// ALL inputs/outputs are FP32 (per reference) — rounds 2/3 NaN'd because we
// read fp32 buffers as bf16. Internally: bf16 MFMA fragments, fp32 accum.
//   Phase A (coop, 256 WGs): enc0 --ring(4)--> enc1  (enc1 seq discarded)
//   Phase B (coop, 256 WGs): dec0 --ring(4)--> dec1 --(delay 4)--> fused FC
// h buffers: 8-plane bf16 rings; enc->dec h_T handoff free (512 % 8 == 0).
// Weights: gathered per-WG from global fp32 -> LDS bf16 MFMA-B fragments at
// kernel start (no weight workspace). d_ws footprint: 3.1 MiB.
// Cross-WG sync: per-batch-group agent-scope counters (release/acquire).
// ============================================================================

using bf16x8 = __attribute__((ext_vector_type(8))) short;   // 8 bf16 = 4 VGPR
using f32x16 = __attribute__((ext_vector_type(16))) float;  // 32x32 mfma acc
using f32x4  = __attribute__((ext_vector_type(4))) float;   // 16x16 mfma acc

#define MFMA32(a, b, c) __builtin_amdgcn_mfma_f32_32x32x16_bf16((a), (b), (c), 0, 0, 0)
#define MFMA16(a, b, c) __builtin_amdgcn_mfma_f32_16x16x32_bf16((a), (b), (c), 0, 0, 0)

static __device__ __forceinline__ uint16_t f2bf(float f) {
  union { float f; uint32_t u; } v; v.f = f;
  uint32_t u = v.u;
  return (uint16_t)((u + 0x7fffu + ((u >> 16) & 1u)) >> 16);  // RNE
}
static __device__ __forceinline__ float sigm(float x) { return 1.0f / (1.0f + __expf(-x)); }
static __device__ __forceinline__ float tanh_f(float x) { return 2.0f / (1.0f + __expf(-2.0f * x)) - 1.0f; }

static __device__ __forceinline__ bf16x8 cvt8(const float* p) {
  bf16x8 r;
#pragma unroll
  for (int i = 0; i < 8; ++i) { uint16_t b = f2bf(p[i]); r[i] = (short)b; }
  return r;
}

// ---------------- workspace layout (bytes); total 3,146,752 B ----------------
static const size_t OFF_CTR = 0;                  // [16] u32 step counters
static const size_t OFF_HB0 = 1024;               // [8][128][512] bf16 h-ring (enc0/dec0)
static const size_t OFF_HB1 = 1024 + 1048576;     // [8][128][512] bf16 h-ring (enc1/dec1)
static const size_t OFF_E0R = 1024 + 2097152;     // [4][128][512] bf16 ring enc0->enc1
static const size_t OFF_D0R = 1024 + 2621440;     // [4][128][512] bf16 ring dec0->dec1

// ---------------- init: zero counters + h-ring plane0 (h_{-1}=0) ------------
__global__ void init_kernel(uint32_t* ctr, uint32_t* h0a, uint32_t* h0b) {
  int i = (int)blockIdx.x * 256 + (int)threadIdx.x;
  if (i < 16) ctr[i] = 0;
  for (int j = i; j < 32768; j += (int)gridDim.x * 256) { h0a[j] = 0; h0b[j] = 0; }
}

// ---------------- pipelined persistent LSTM layer kernel ----------------
struct PJob {
  const float* whh;       // [2048][512] fp32
  const float* wih;       // [2048][KX] fp32
  const float* bih;       // [2048] fp32
  const float* bhh;       // [2048] fp32
  const float* xf;        // fp32 x [128][512][KX] (enc0/dec0) or null
  const uint16_t* xring;  // [4][128][512] bf16 ring (enc1/dec1) or null
  uint16_t* hring;        // [8][128][512] bf16; plane0 = h_{-1}
  const float* c0;        // [128][512] fp32 or null (zeros)
  uint16_t* ringout;      // [4][128][512] bf16 or null
  uint32_t* ownc;         // [2] own step counters (per batch-group)
  uint32_t* prodc;        // [2] producer counters or null (ring input ready)
  uint32_t* consc;        // [2] consumer counters or null (ring free / FC src)
  const float* fcw;       // [128][512] fp32 or null (dec0 only)
  const float* fcb;       // [128] fp32
  const uint16_t* fchr;   // dec1 h-ring (FC input)
  float* out;             // d_out [128][512][128] fp32
  int KX;                 // 128 or 512
  int shift;              // 1 for dec0 (input = x shifted right one step)
  int tsteps;             // 512, or 516 for dec0 (FC drain tail)
};

static __device__ __forceinline__ void spin_acq(uint32_t* c, uint32_t thr) {
  while (__hip_atomic_load(c, __ATOMIC_RELAXED, __HIP_MEMORY_SCOPE_AGENT) < thr)
    __builtin_amdgcn_s_sleep(1);
  (void)__hip_atomic_load(c, __ATOMIC_ACQUIRE, __HIP_MEMORY_SCOPE_AGENT);
}

__global__ void __launch_bounds__(256, 1) lstm_pipe(PJob j0, PJob j1) {
  const PJob J = ((int)blockIdx.x < 128) ? j0 : j1;
  const int lb = (int)blockIdx.x & 127;
  const int bg = lb >> 6, u = lb & 63, b0 = bg * 64;
  const int tid = (int)threadIdx.x;
  const int wv = tid >> 6, ln = tid & 63;

  __shared__ __align__(16) uint16_t Wl[40960];  // 64K rec weights + 16K fcW (80 KiB)
  __shared__ float gb[2][64][33];               // k-partial gates (+1 pad)
  __shared__ float cst[64][9];                  // fp32 cell state (+1 pad)

  const int KX = J.KX;
  const int NTX = KX >> 5;          // x k-blocks per k-half (4 or 16)
  const int HS = (16 + NTX) * 512;  // packed elems per k-half

  // ---- gather [Whh ; Wih] chunk u from global fp32 -> LDS bf16 B-frags ----
  // LDS elem e = kh*HS + kt*512 + lane*8 + j. col=lane&31 -> packed gate-col;
  // orig row = (col>>3)*512 + u*8 + (col&7). m = kt*16 + (lane>>5)*8 + j:
  // m<256 -> Whh k = kh*256+m ; else Wih k = kh*(KX/2)+(m-256).
  {
    const int nfrag = (2 * HS) >> 3;
    for (int f = tid; f < nfrag; f += 256) {
      int lane = f & 63;
      int kt2 = f >> 6;                       // kh*(16+NTX) + kt
      int kh = (kt2 >= 16 + NTX) ? 1 : 0;
      int kt = kt2 - kh * (16 + NTX);
      int col = lane & 31;
      int wrow = ((col >> 3) << 9) + (u << 3) + (col & 7);
      int m = (kt << 4) + ((lane >> 5) << 3);
      const float* src = (m < 256)
          ? J.whh + (size_t)wrow * 512 + (kh << 8) + m
          : J.wih + (size_t)wrow * KX + kh * (KX >> 1) + (m - 256);
      union { uint16_t h[8]; ulonglong2 v; } tmp;
#pragma unroll
      for (int j = 0; j < 8; ++j) tmp.h[j] = f2bf(src[j]);
      *(ulonglong2*)(Wl + (size_t)f * 8) = tmp.v;
    }
  }

  // FC assignment: dec0 WGs with u<8; wave wv owns out tile (ftr, ftc)
  const int isfc = (J.fcw != nullptr) && (u < 8);
  const int wgti = bg * 8 + u;             // 0..15
  const int ftc = wgti & 7;
  const int ftr = 2 * wv + (wgti >> 3);    // 0..7
  const int fcol = ftc * 16 + (ln & 15);
  const int farow = ftr * 16 + (ln & 15);
  float fbv = 0.0f;
  if (isfc) {
    fbv = J.fcb[fcol];
    // fcW B-frags (16x16x32): LDS e = kt*512 + lane*8 + j;
    // row = ftc*16 + (lane&15), k = kt*32 + (lane>>4)*8 + j
    for (int f = tid; f < 1024; f += 256) {
      int lane = f & 63, kt = f >> 6;
      int row = ftc * 16 + (lane & 15);
      int k = (kt << 5) + ((lane >> 4) << 3);
      const float* src = J.fcw + (size_t)row * 512 + k;
      union { uint16_t h[8]; ulonglong2 v; } tmp;
#pragma unroll
      for (int j = 0; j < 8; ++j) tmp.h[j] = f2bf(src[j]);
      *(ulonglong2*)(Wl + 32768 + (size_t)f * 8) = tmp.v;
    }
  }

  // ---- per-thread epilogue assignment: 2 hidden units ----
  const int rl = tid >> 2, ul2 = (tid & 3) * 2, bE = b0 + rl;
  const int hu = u * 8 + ul2;  // original hidden-unit index (pair base)
  const float Bi0 = J.bih[hu] + J.bhh[hu];
  const float Bi1 = J.bih[hu + 1] + J.bhh[hu + 1];
  const float Bf0 = J.bih[512 + hu] + J.bhh[512 + hu];
  const float Bf1 = J.bih[513 + hu] + J.bhh[513 + hu];
  const float Bg0 = J.bih[1024 + hu] + J.bhh[1024 + hu];
  const float Bg1 = J.bih[1025 + hu] + J.bhh[1025 + hu];
  const float Bo0 = J.bih[1536 + hu] + J.bhh[1536 + hu];
  const float Bo1 = J.bih[1537 + hu] + J.bhh[1537 + hu];
  {
    float c0v = 0.f, c1v = 0.f;
    if (J.c0) {
      c0v = J.c0[(size_t)bE * 512 + hu];
      c1v = J.c0[(size_t)bE * 512 + hu + 1];
    }
    cst[rl][ul2] = c0v;
    cst[rl][ul2 + 1] = c1v;
  }
  __syncthreads();

  const int mt = wv & 1, kh = wv >> 1;
  const int arow = b0 + mt * 32 + (ln & 31);
  const size_t hbase = (size_t)arow * 512 + (size_t)kh * 256 + ((ln >> 5) << 3);
  const uint16_t* wlh = Wl + (size_t)kh * HS + (size_t)ln * 8;
  const uint16_t* wlx = wlh + 16 * 512;
  const size_t hwr = (size_t)bE * 512 + hu;
  const int tsteps = J.tsteps;

  for (int t = 0; t < tsteps; ++t) {
    // ---- cross-WG waits (data barrier + pipeline throttles) ----
    if (tid == 0) {
      if (t > 0 && t <= 512) spin_acq(J.ownc + bg, 64u * (uint32_t)t);
      if (J.prodc && t < 512) spin_acq(J.prodc + bg, 64u * (uint32_t)(t + 1));
      if (J.consc && t >= 4 && t < 512) spin_acq(J.consc + bg, 64u * (uint32_t)(t - 3));
      if (J.fcw && t >= 4) {  // FC needs dec1 h(t-4), both batch-groups
        spin_acq(J.consc + 0, 64u * (uint32_t)(t - 3));
        spin_acq(J.consc + 1, 64u * (uint32_t)(t - 3));
      }
    }
    __syncthreads();

    if (t < 512) {
      f32x16 acc;
#pragma unroll
      for (int r = 0; r < 16; ++r) acc[r] = 0.0f;
      // h-part: K 256 per half, from 8-plane bf16 ring
      const uint16_t* hb = J.hring + (size_t)(t & 7) * 65536 + hbase;
#pragma unroll 4
      for (int kt = 0; kt < 16; ++kt) {
        bf16x8 af = *(const bf16x8*)(hb + kt * 16);
        bf16x8 bw = *(const bf16x8*)(wlh + kt * 512);
        acc = MFMA32(af, bw, acc);
      }
      // x-part
      if (J.xring) {  // previous layer's h ring (bf16, 512 wide)
        const uint16_t* xb = J.xring + (size_t)(t & 3) * 65536 + hbase;
#pragma unroll 4
        for (int kt = 0; kt < 16; ++kt) {
          bf16x8 af = *(const bf16x8*)(xb + kt * 16);
          bf16x8 bw = *(const bf16x8*)(wlx + kt * 512);
          acc = MFMA32(af, bw, acc);
        }
      } else {  // global fp32 x, convert on the fly
        const int tx = t - J.shift;
        if (tx >= 0) {
          const float* xb = J.xf + (size_t)arow * (512 * (size_t)KX) +
                            (size_t)tx * KX + kh * (KX >> 1) + ((ln >> 5) << 3);
          for (int kt = 0; kt < NTX; ++kt) {
            bf16x8 af = cvt8(xb + kt * 16);
            bf16x8 bw = *(const bf16x8*)(wlx + kt * 512);
            acc = MFMA32(af, bw, acc);
          }
        }
      }
#pragma unroll
      for (int r = 0; r < 16; ++r) {
        int crow = (r & 3) + 8 * (r >> 2) + 4 * (ln >> 5);
        gb[kh][mt * 32 + crow][ln & 31] = acc[r];
      }
      __syncthreads();

      // ---- epilogue: 2 hidden units per thread ----
      float i0 = sigm(gb[0][rl][ul2]      + gb[1][rl][ul2]      + Bi0);
      float i1 = sigm(gb[0][rl][ul2 + 1]  + gb[1][rl][ul2 + 1]  + Bi1);
      float f0 = sigm(gb[0][rl][8 + ul2]  + gb[1][rl][8 + ul2]  + Bf0);
      float f1 = sigm(gb[0][rl][9 + ul2]  + gb[1][rl][9 + ul2]  + Bf1);
      float g0 = tanh_f(gb[0][rl][16 + ul2] + gb[1][rl][16 + ul2] + Bg0);
      float g1 = tanh_f(gb[0][rl][17 + ul2] + gb[1][rl][17 + ul2] + Bg1);
      float o0 = sigm(gb[0][rl][24 + ul2] + gb[1][rl][24 + ul2] + Bo0);
      float o1 = sigm(gb[0][rl][25 + ul2] + gb[1][rl][25 + ul2] + Bo1);
      float cc0 = f0 * cst[rl][ul2]     + i0 * g0;
      float cc1 = f1 * cst[rl][ul2 + 1] + i1 * g1;
      cst[rl][ul2] = cc0;
      cst[rl][ul2 + 1] = cc1;
      float h0 = o0 * tanh_f(cc0);
      float h1 = o1 * tanh_f(cc1);
      uint32_t hv = (uint32_t)f2bf(h0) | ((uint32_t)f2bf(h1) << 16);
      *(uint32_t*)(J.hring + (size_t)((t + 1) & 7) * 65536 + hwr) = hv;
      if (J.ringout)
        *(uint32_t*)(J.ringout + (size_t)(t & 3) * 65536 + hwr) = hv;

      __syncthreads();  // each wave drains its vmem stores before the release
      if (tid == 0)
        __hip_atomic_fetch_add(J.ownc + bg, 1u, __ATOMIC_RELEASE, __HIP_MEMORY_SCOPE_AGENT);
    }

    // ---- fused FC head: out[:, t-4] = dec1_h(t-4) @ fcW^T + fcb (fp32) ----
    if (isfc && t >= 4) {
      const int tf = t - 4;
      const uint16_t* ha = J.fchr + (size_t)((tf + 1) & 7) * 65536 +
                           (size_t)farow * 512 + ((ln >> 4) << 3);
      const uint16_t* wb = Wl + 32768 + (size_t)ln * 8;
      f32x4 fa;
      fa[0] = fa[1] = fa[2] = fa[3] = 0.0f;
#pragma unroll 4
      for (int kt = 0; kt < 16; ++kt) {
        bf16x8 a = *(const bf16x8*)(ha + kt * 32);
        bf16x8 b = *(const bf16x8*)(wb + kt * 512);
        fa = MFMA16(a, b, fa);
      }
#pragma unroll
      for (int r = 0; r < 4; ++r) {
        int row = ftr * 16 + ((ln >> 4) << 2) + r;  // batch index
        J.out[((size_t)row * 512 + tf) * 128 + fcol] = fa[r] + fbv;
      }
    }
  }
}

// ---------------- host launch ----------------
extern "C" void kernel_launch(void* const* d_in, const int* in_sizes, int n_in,
                              void* d_out, int out_size, void* d_ws, size_t ws_size,
                              hipStream_t stream) {
  (void)in_sizes; (void)n_in; (void)out_size; (void)ws_size;
  uint8_t* ws = (uint8_t*)d_ws;
  const float* x     = (const float*)d_in[0];
  const float* c_dec = (const float*)d_in[1];
  const float* W[16];
  for (int i = 0; i < 16; ++i) W[i] = (const float*)d_in[2 + i];
  // layer order in d_in: enc0{wih,whh,bih,bhh} enc1{...} dec0{...} dec1{...}
  const float* fcW = (const float*)d_in[18];
  const float* fcb = (const float*)d_in[19];

  uint32_t* CTR = (uint32_t*)(ws + OFF_CTR);
  uint16_t* HB0 = (uint16_t*)(ws + OFF_HB0);
  uint16_t* HB1 = (uint16_t*)(ws + OFF_HB1);
  uint16_t* E0R = (uint16_t*)(ws + OFF_E0R);
  uint16_t* D0R = (uint16_t*)(ws + OFF_D0R);
  uint32_t* CE0 = CTR + 0, *CE1 = CTR + 2, *CD0 = CTR + 4, *CD1 = CTR + 6;

  // 1) zero counters + h-ring plane0 (h_{-1} = 0)
  hipLaunchKernelGGL(init_kernel, dim3(128), dim3(256), 0, stream,
                     CTR, (uint32_t*)HB0, (uint32_t*)HB1);

  // 2) phase A: enc0 (x -> E0R, h in HB0) || enc1 (E0R -> HB1; seq discarded)
  {
    PJob a; a.whh = W[1]; a.wih = W[0]; a.bih = W[2]; a.bhh = W[3];
    a.xf = x; a.xring = nullptr; a.hring = HB0; a.c0 = nullptr; a.ringout = E0R;
    a.ownc = CE0; a.prodc = nullptr; a.consc = CE1;
    a.fcw = nullptr; a.fcb = nullptr; a.fchr = nullptr; a.out = nullptr;
    a.KX = 128; a.shift = 0; a.tsteps = 512;
    PJob b; b.whh = W[5]; b.wih = W[4]; b.bih = W[6]; b.bhh = W[7];
    b.xf = nullptr; b.xring = E0R; b.hring = HB1; b.c0 = nullptr; b.ringout = nullptr;
    b.ownc = CE1; b.prodc = CE0; b.consc = nullptr;
    b.fcw = nullptr; b.fcb = nullptr; b.fchr = nullptr; b.out = nullptr;
    b.KX = 512; b.shift = 0; b.tsteps = 512;
    void* args[2] = { &a, &b };
    hipLaunchCooperativeKernel((const void*)lstm_pipe, dim3(256), dim3(256), args, 0, stream);
  }

  // 3) phase B: dec0 (shift(x) -> D0R, h0 = enc0 hT in HB0 plane0, c0=c_dec[0],
  //    + fused FC from dec1's ring) || dec1 (D0R -> HB1, h0 = enc1 hT, c0=c_dec[1])
  {
    PJob a; a.whh = W[9]; a.wih = W[8]; a.bih = W[10]; a.bhh = W[11];
    a.xf = x; a.xring = nullptr; a.hring = HB0; a.c0 = c_dec; a.ringout = D0R;
    a.ownc = CD0; a.prodc = nullptr; a.consc = CD1;
    a.fcw = fcW; a.fcb = fcb; a.fchr = HB1; a.out = (float*)d_out;
    a.KX = 128; a.shift = 1; a.tsteps = 516;
    PJob b; b.whh = W[13]; b.wih = W[12]; b.bih = W[14]; b.bhh = W[15];
    b.xf = nullptr; b.xring = D0R; b.hring = HB1; b.c0 = c_dec + 65536; b.ringout = nullptr;
    b.ownc = CD1; b.prodc = CD0; b.consc = nullptr;
    b.fcw = nullptr; b.fcb = nullptr; b.fchr = nullptr; b.out = nullptr;
    b.KX = 512; b.shift = 0; b.tsteps = 512;
    void* args[2] = { &a, &b };
    hipLaunchCooperativeKernel((const void*)lstm_pipe, dim3(256), dim3(256), args, 0, stream);
  }
}